// Round 16
// baseline (37.052 us; speedup 1.0000x reference)
//
#include <hip/hip_runtime.h>

// CubeLens: radial lens deflection + bilinear gather + 4x4 avg pool.
// C=64, NS=256, NL=192, UPS=4. Output (64,192,192) fp32.
//
// R16: SOLO-THREAD gather. R15's measurement: transpose+overhead = 3.5us,
// main = 25us. Phased/cooperative designs (shfl tables, LDS weights,
// barriers) serialized ~417 CU-cycles/pixel. This round: thread=(px,c8)
// does EVERYTHING alone — 16 taps geometry + per-tap 4 coalesced f16x8
// corner loads + local bilinear weights. Zero LDS, zero barriers, zero
// shfl, zero modes. 64-thread blocks x 4608, ~16 waves/CU, independent
// latency-hiding per wave.
//   k1: fp32->fp16 channel-last transpose (unchanged, 3.5us incl launch).
//   k2: cubelens_solo.

#define NSRC 256
#define NLENS 192
#define NPIX (NLENS * NLENS)     // 36864
#define CSZ  64
#define NBLK (NPIX / 8)          // 4608 blocks of 8 px (64 thr)
#define NTTILE (NSRC * NSRC / 64)  // 1024 transpose tiles

typedef float    f32x4 __attribute__((ext_vector_type(4)));
typedef _Float16 f16x8 __attribute__((ext_vector_type(8)));

// ---------------- fallback (round-1 kernel, used only if ws too small) ------
__global__ __launch_bounds__(256) void cubelens_fallback(
    const float* __restrict__ src, const float* __restrict__ theta_p,
    float* __restrict__ out)
{
    const float tE = theta_p[0];
    const int pix = blockIdx.x * 256 + threadIdx.x;
    const int c0  = blockIdx.y * 8;
    const int lx  = pix % NLENS;
    const int ly  = pix / NLENS;
    float acc[8];
#pragma unroll
    for (int c = 0; c < 8; ++c) acc[c] = 0.0f;
    const float* __restrict__ srcg = src + (size_t)c0 * (NSRC * NSRC);
#pragma unroll
    for (int uy = 0; uy < 4; ++uy) {
        const float thy = ((float)(ly * 4 + uy) - 383.5f) * 0.01f;
#pragma unroll
        for (int ux = 0; ux < 4; ++ux) {
            const float thx = ((float)(lx * 4 + ux) - 383.5f) * 0.01f;
            const float r  = sqrtf(thx * thx + thy * thy) + 1e-8f;
            const float fx = (thx - (tE * thx) / r) / 0.02f + 127.5f;
            const float fy = (thy - (tE * thy) / r) / 0.02f + 127.5f;
            const bool inb = (fx >= 0.0f) & (fx <= 255.0f) &
                             (fy >= 0.0f) & (fy <= 255.0f);
            if (!inb) continue;
            int x0 = min(max((int)floorf(fx), 0), 254);
            int y0 = min(max((int)floorf(fy), 0), 254);
            const float wx = fminf(fmaxf(fx - (float)x0, 0.0f), 1.0f);
            const float wy = fminf(fmaxf(fy - (float)y0, 0.0f), 1.0f);
            const float w00 = (1.0f - wy) * (1.0f - wx);
            const float w01 = (1.0f - wy) * wx;
            const float w10 = wy * (1.0f - wx);
            const float w11 = wy * wx;
            const float* __restrict__ p = srcg + y0 * NSRC + x0;
#pragma unroll
            for (int c = 0; c < 8; ++c) {
                const float* __restrict__ pc = p + c * (NSRC * NSRC);
                acc[c] += w00 * pc[0] + w01 * pc[1]
                        + w10 * pc[NSRC] + w11 * pc[NSRC + 1];
            }
        }
    }
#pragma unroll
    for (int c = 0; c < 8; ++c)
        out[(size_t)(c0 + c) * NPIX + pix] = acc[c] * 0.0625f;
}

// ---------------- k1: transpose (c,p) fp32 -> (p,c) fp16, XCD swizzle -------
__global__ __launch_bounds__(256) void transpose_kernel(
    const float* __restrict__ src, _Float16* __restrict__ ws)
{
    __shared__ float tile[CSZ][65];
    const int b = blockIdx.x;
    const int tileid = (b & 7) * (NTTILE / 8) + (b >> 3);
    const int p0 = tileid * 64;
    const int t  = threadIdx.x;
    {
        const int crow = t >> 4;
        const int px4  = (t & 15) * 4;
#pragma unroll
        for (int i = 0; i < 4; ++i) {
            const int c = crow + 16 * i;
            const f32x4 v = __builtin_nontemporal_load(
                (const f32x4*)(src + (size_t)c * (NSRC * NSRC) + p0 + px4));
            tile[c][px4 + 0] = v.x; tile[c][px4 + 1] = v.y;
            tile[c][px4 + 2] = v.z; tile[c][px4 + 3] = v.w;
        }
    }
    __syncthreads();
    {
        const int c8 = (t & 7) * 8;
        const int pr = t >> 3;
#pragma unroll
        for (int i = 0; i < 2; ++i) {
            const int p = pr + 32 * i;
            f16x8 h;
#pragma unroll
            for (int k = 0; k < 8; ++k) h[k] = (_Float16)tile[c8 + k][p];
            *(f16x8*)(ws + (size_t)(p0 + p) * CSZ + c8) = h;
        }
    }
}

// ---------------- k2: solo-thread lens gather -------------------------------
__global__ __launch_bounds__(64, 4) void cubelens_solo(
    const _Float16* __restrict__ ws,    // (256,256,64) fp16
    const float* __restrict__ theta_p,
    float* __restrict__ out)            // (64,192,192) fp32
{
    const float tE = theta_p[0];
    const int b = blockIdx.x;
    const int pixblock = (b & 7) * (NBLK / 8) + (b >> 3);   // XCD swizzle
    const int p0 = pixblock * 8;
    const int t  = threadIdx.x;         // 0..63
    const int pi = t >> 3;              // pixel in block (8-lane group)
    const int c8 = t & 7;               // channel group: 8*c8 .. 8*c8+7

    const int p  = p0 + pi;
    const int lx = p % NLENS, ly = p / NLENS;
    const float bx0 = (float)(lx * 4) - 383.5f;
    const float by0 = (float)(ly * 4) - 383.5f;

    float acc[8];
#pragma unroll
    for (int e = 0; e < 8; ++e) acc[e] = 0.0f;

    const _Float16* __restrict__ wsc = ws + c8 * 8;

#pragma unroll
    for (int tap = 0; tap < 16; ++tap) {
        const float thy = (by0 + (float)(tap >> 2)) * 0.01f;
        const float thx = (bx0 + (float)(tap & 3))  * 0.01f;
        const float r  = sqrtf(thx * thx + thy * thy) + 1e-8f;
        const float fx = (thx - (tE * thx) / r) / 0.02f + 127.5f;
        const float fy = (thy - (tE * thy) / r) / 0.02f + 127.5f;
        const bool inb = (fx >= 0.0f) & (fx <= 255.0f) &
                         (fy >= 0.0f) & (fy <= 255.0f);
        if (inb) {                       // uniform across the 8-lane px group
            int x0 = min(max((int)floorf(fx), 0), 254);
            int y0 = min(max((int)floorf(fy), 0), 254);
            const float wx = fminf(fmaxf(fx - (float)x0, 0.0f), 1.0f);
            const float wy = fminf(fmaxf(fy - (float)y0, 0.0f), 1.0f);
            const float w00 = (1.0f - wy) * (1.0f - wx);
            const float w01 = (1.0f - wy) * wx;
            const float w10 = wy * (1.0f - wx);
            const float w11 = wy * wx;
            const _Float16* __restrict__ pp = wsc + (y0 * NSRC + x0) * CSZ;
            const f16x8 v00 = *(const f16x8*)(pp);
            const f16x8 v01 = *(const f16x8*)(pp + CSZ);
            const f16x8 v10 = *(const f16x8*)(pp + NSRC * CSZ);
            const f16x8 v11 = *(const f16x8*)(pp + NSRC * CSZ + CSZ);
#pragma unroll
            for (int e = 0; e < 8; ++e)
                acc[e] += w00 * (float)v00[e] + w01 * (float)v01[e]
                        + w10 * (float)v10[e] + w11 * (float)v11[e];
        }
    }

    // direct stores: element e -> out[(8*c8+e)*NPIX + p]; lanes with the
    // same c8 cover 8 consecutive pixels -> 32B segments per wave-store.
    float* __restrict__ op = out + (size_t)(c8 * 8) * NPIX + p;
#pragma unroll
    for (int e = 0; e < 8; ++e)
        __builtin_nontemporal_store(acc[e] * 0.0625f, op + (size_t)e * NPIX);
}

extern "C" void kernel_launch(void* const* d_in, const int* in_sizes, int n_in,
                              void* d_out, int out_size, void* d_ws, size_t ws_size,
                              hipStream_t stream) {
    const float* src   = (const float*)d_in[0];
    const float* theta = (const float*)d_in[1];
    float* out = (float*)d_out;

    const size_t need = (size_t)CSZ * NSRC * NSRC * sizeof(_Float16);  // 8.4 MB
    if (ws_size >= need) {
        _Float16* ws = (_Float16*)d_ws;
        transpose_kernel<<<dim3(NTTILE), dim3(256), 0, stream>>>(src, ws);
        cubelens_solo<<<dim3(NBLK), dim3(64), 0, stream>>>(ws, theta, out);
    } else {
        cubelens_fallback<<<dim3(NPIX / 256, 8), dim3(256), 0, stream>>>(src, theta, out);
    }
}